// Round 11
// baseline (137.689 us; speedup 1.0000x reference)
//
#include <hip/hip_runtime.h>
#include <hip/hip_bf16.h>
#include <math.h>

#define L_SEQ 1024
#define BSZ 8
#define EMB 512
#define NH 8
#define DQ 64
#define BH 64          // BSZ*NH
#define NQKV 1536      // 3*NH*DQ

// Q is pre-scaled by (emb_dim/n_head)^-0.5 * log2(e) so that
// softmax numerator = exp2(mfma_score) with zero extra VALU per element.
#define SCALE_Q 0.18033688f

typedef __attribute__((ext_vector_type(8))) short short8;   // 8 bf16 = 4 VGPR
typedef __attribute__((ext_vector_type(4))) short short4v;  // 4 bf16 = 2 VGPR
typedef __attribute__((ext_vector_type(4))) float f32x4;

#define GPTR(x) ((const __attribute__((address_space(1))) void*)(x))
#define LPTR(x) ((__attribute__((address_space(3))) void*)(x))

// PV matmul: 16x16x16 bf16 MFMA. B-fragment layout (k = quad*4+e) matches
// the S^T C-layout natively -> no cross-lane shuffles needed for P.
#if __has_builtin(__builtin_amdgcn_mfma_f32_16x16x16bf16_1k)
#define MFMA16(acc, a, b) \
  acc = __builtin_amdgcn_mfma_f32_16x16x16bf16_1k(a, b, acc, 0, 0, 0)
#else
#define MFMA16(acc, a, b) \
  asm volatile("v_mfma_f32_16x16x16_bf16 %0, %1, %2, %0" \
               : "+v"(acc) : "v"(a), "v"(b))
#endif

__device__ __forceinline__ unsigned short bf16u(float x) {
  __hip_bfloat16 h = __float2bfloat16(x);
  return *(unsigned short*)&h;
}

// ---------------------------------------------------------------------------
// Kernel 0: f32 -> bf16 convert of emb (8192x512) and W (1536x512).
// Block 0 also zero-inits Oacc/cnt (stream order guarantees init before
// attn_one's blocks race on cnt).
// ---------------------------------------------------------------------------
__global__ __launch_bounds__(256) void to_bf16(
    const float* __restrict__ emb, const float* __restrict__ W,
    unsigned short* __restrict__ embB, unsigned short* __restrict__ WB,
    float* __restrict__ Oacc, int* __restrict__ cnt) {
  const int tid = threadIdx.x;
  if (blockIdx.x == 0) {
    for (int i = tid; i < BH * DQ; i += 256) Oacc[i] = 0.f;
    if (tid < BH) cnt[tid] = 0;
  }
  const size_t t = (size_t)blockIdx.x * 256 + tid;
  size_t base = t * 8;
  const float* src;
  unsigned short* dst;
  size_t off;
  if (base < (size_t)8192 * 512) { src = emb; dst = embB; off = base; }
  else { src = W; dst = WB; off = base - (size_t)8192 * 512; }
  float4 v0 = *(const float4*)&src[off];
  float4 v1 = *(const float4*)&src[off + 4];
  short8 o;
  o[0] = bf16u(v0.x); o[1] = bf16u(v0.y); o[2] = bf16u(v0.z); o[3] = bf16u(v0.w);
  o[4] = bf16u(v1.x); o[5] = bf16u(v1.y); o[6] = bf16u(v1.z); o[7] = bf16u(v1.w);
  *(short8*)&dst[off] = o;
}

// ---------------------------------------------------------------------------
// Kernel A: QKV projection, bf16 MFMA (m97 pattern). Q gets SCALE_Q folded in.
// (round-5 version, verbatim: two-pass epilogue, 33 KB LDS, XCD swizzle)
// ---------------------------------------------------------------------------
__global__ __launch_bounds__(256, 4) void qkv_mfma(
    const unsigned short* __restrict__ A,   // embB [8192][512]
    const unsigned short* __restrict__ B,   // WB   [1536][512]
    const float* __restrict__ bias,
    unsigned short* __restrict__ Qb, unsigned short* __restrict__ Kb,
    unsigned short* __restrict__ Vb) {
  __shared__ __align__(16) unsigned short As[128][32];  // 8 KB, unpadded
  __shared__ __align__(16) unsigned short Bs[128][32];  // 8 KB
  __shared__ __align__(16) unsigned short Cs[128][68];  // 17 KB, +4 pad
  const int tid = threadIdx.x;
  const int wave = tid >> 6, lane = tid & 63;
  const int quad = lane >> 4, col = lane & 15;
  const int wr = wave >> 1, wc = wave & 1;
  const int id = blockIdx.x;
  const int sid = (id & 7) * 96 + (id >> 3);
  const int mb = sid / 12, nb = sid - mb * 12;
  const int m0 = mb * 128, n0 = nb * 128;
  const int r16 = lane >> 2, q4 = lane & 3;

  f32x4 acc[4][4] = {};

  for (int kt = 0; kt < EMB; kt += 32) {
    __syncthreads();
#pragma unroll
    for (int c = 0; c < 2; ++c) {
      const int rowA = (c * 4 + wave) * 16;
      __builtin_amdgcn_global_load_lds(
          GPTR(A + (size_t)(m0 + rowA + r16) * EMB + kt + q4 * 8),
          LPTR(&As[rowA][0]), 16, 0, 0);
      __builtin_amdgcn_global_load_lds(
          GPTR(B + (size_t)(n0 + rowA + r16) * EMB + kt + q4 * 8),
          LPTR(&Bs[rowA][0]), 16, 0, 0);
    }
    __syncthreads();
    short8 af[4], bf[4];
#pragma unroll
    for (int i = 0; i < 4; ++i)
      af[i] = *(const short8*)&As[wr * 64 + i * 16 + col][quad * 8];
#pragma unroll
    for (int j = 0; j < 4; ++j)
      bf[j] = *(const short8*)&Bs[wc * 64 + j * 16 + col][quad * 8];
#pragma unroll
    for (int i = 0; i < 4; ++i)
#pragma unroll
      for (int j = 0; j < 4; ++j)
        acc[i][j] =
            __builtin_amdgcn_mfma_f32_16x16x32_bf16(af[i], bf[j], acc[i][j],
                                                    0, 0, 0);
  }

  const int bb = lane >> 3, oct = lane & 7;
#pragma unroll
  for (int h = 0; h < 2; ++h) {
    __syncthreads();
    if (wc == h) {
#pragma unroll
      for (int j = 0; j < 4; ++j) {
        const int n = j * 16 + col;
        const float bj = bias[n0 + h * 64 + n];
        const bool isQ = (((n0 + h * 64 + n) >> 6) % 3) == 0;
#pragma unroll
        for (int i = 0; i < 4; ++i) {
          const int mrow = wr * 64 + i * 16 + quad * 4;
#pragma unroll
          for (int r = 0; r < 4; ++r) {
            float val = acc[i][j][r] + bj;
            if (isQ) val *= SCALE_Q;
            Cs[mrow + r][n] = bf16u(val);
          }
        }
      }
    }
    __syncthreads();
    const int G = (n0 >> 6) + h;
    const int hd = G / 3, sel = G % 3;
    unsigned short* dst = (sel == 0) ? Qb : (sel == 1) ? Kb : Vb;
#pragma unroll
    for (int e = 0; e < 4; ++e) {
      const int l = wave * 4 + e;
      short8 v = *(const short8*)&Cs[l * 8 + bb][oct * 8];
      const int lglob = (m0 >> 3) + l;
      *(short8*)&dst[(((size_t)(bb * NH + hd)) * L_SEQ + lglob) * DQ + oct * 8] = v;
    }
  }
}

// ---------------------------------------------------------------------------
// Kernel B (v14): single-sweep attention, QUADRANT work partition.
// R10 analysis: each of 4 waves read IDENTICAL K/V LDS data (fragments
// depend on sub/col/quad, not wave) -> 4x redundant reads; LDS pipe
// ~3840 cyc/tile vs MFMA 832 -> LDS-issue bound. Fix: wave owns a
// (4 subs x 4 qg) quadrant: sw=(wave&1)*4 keys-subs, qw=(wave>>1)*4
// q-groups. Per wave/tile: K-reads 16->8, tr-reads 32->16, MFMA/exp2
// counts unchanged. Y[4qg][4dg] (64 VGPR) + Q[4qg] (32 VGPR) ~ 176 total.
// End: cross-wave z-reduce via zred[4][64] (two waves per l), then each
// wave folds invz into its Y quadrant; red/atomicAdd composes the four
// (l-half x key-half) partials exactly. All staging/fragment/tr-read
// machinery byte-identical to R10 (validated).
// ---------------------------------------------------------------------------
__global__ __launch_bounds__(256) void attn_one(
    const unsigned short* __restrict__ Qb, const unsigned short* __restrict__ Kb,
    const unsigned short* __restrict__ Vb,
    const float* __restrict__ gnw, const float* __restrict__ gnb,
    float* __restrict__ Oacc, int* __restrict__ cnt, float* __restrict__ out) {
  const int bh = blockIdx.x & 63;   // blk%8 = bh%8 -> same-bh blocks same XCD
  const int qc = blockIdx.x >> 6;   // 0..7, 128 q-rows each
  const int tid = threadIdx.x;
  const int wave = tid >> 6, lane = tid & 63;
  const int quad = lane >> 4, col = lane & 15;
  const int sw = (wave & 1) * 4;    // this wave's key-sub base (0 or 4)
  const int qw = (wave >> 1) * 4;   // this wave's q-group base (0 or 4)

  __shared__ __align__(16) unsigned short Ks[2][128][72];  // 36864 B
  __shared__ __align__(16) unsigned short Vs[2][8192];     // 32768 B subtiled
  __shared__ float zred[4][64];
  __shared__ float red[4][64];
  __shared__ int lastFlag;

  const unsigned short* kbase = &Kb[(size_t)bh * L_SEQ * DQ];
  const unsigned short* vbase = &Vb[(size_t)bh * L_SEQ * DQ];

  // Q as B-operand fragments for this wave's 4 q-groups
  short8 qbf[4][2];
#pragma unroll
  for (int qg = 0; qg < 4; ++qg) {
    const unsigned short* qp =
        &Qb[((size_t)bh * L_SEQ + qc * 128 + (qw + qg) * 16 + col) * DQ];
    qbf[qg][0] = *(const short8*)&qp[quad * 8];
    qbf[qg][1] = *(const short8*)&qp[32 + quad * 8];
  }

  const int srow = tid >> 3;        // staging row 0..31 (+32*chunk)
  const int scol = (tid & 7) * 8;   // staging col (shorts)

  float zacc[4] = {0.f, 0.f, 0.f, 0.f};
  f32x4 Y[4][4] = {};               // [qg][dg]

  // V subtile store offsets: elem (k,d) -> ((k>>4)*4 + (d>>4))*256
  //                                        + (k&15)*16 + (d&15)
  int voff[4];
#pragma unroll
  for (int c = 0; c < 4; ++c) {
    const int kdx = c * 32 + srow;
    voff[c] = ((kdx >> 4) * 4 + (scol >> 4)) * 256 + (kdx & 15) * 16 + (scol & 15);
  }

  short8 kst0, kst1, kst2, kst3, vst0, vst1, vst2, vst3;
  {  // prefetch tile 0 (K and V tiles are 16 KB contiguous)
    kst0 = *(const short8*)(kbase + (size_t)tid * 8);
    kst1 = *(const short8*)(kbase + 2048 + (size_t)tid * 8);
    kst2 = *(const short8*)(kbase + 4096 + (size_t)tid * 8);
    kst3 = *(const short8*)(kbase + 6144 + (size_t)tid * 8);
    vst0 = *(const short8*)(vbase + (size_t)tid * 8);
    vst1 = *(const short8*)(vbase + 2048 + (size_t)tid * 8);
    vst2 = *(const short8*)(vbase + 4096 + (size_t)tid * 8);
    vst3 = *(const short8*)(vbase + 6144 + (size_t)tid * 8);
  }

  for (int kt = 0; kt < 8; ++kt) {
    const int buf = kt & 1;
    *(short8*)&Ks[buf][srow][scol] = kst0;
    *(short8*)&Ks[buf][32 + srow][scol] = kst1;
    *(short8*)&Ks[buf][64 + srow][scol] = kst2;
    *(short8*)&Ks[buf][96 + srow][scol] = kst3;
    *(short8*)&Vs[buf][voff[0]] = vst0;
    *(short8*)&Vs[buf][voff[1]] = vst1;
    *(short8*)&Vs[buf][voff[2]] = vst2;
    *(short8*)&Vs[buf][voff[3]] = vst3;
    __syncthreads();
    if (kt + 1 < 8) {  // post-barrier prefetch: in flight through compute
      const unsigned short* nk = kbase + (size_t)(kt + 1) * 8192;
      const unsigned short* nv = vbase + (size_t)(kt + 1) * 8192;
      kst0 = *(const short8*)(nk + (size_t)tid * 8);
      kst1 = *(const short8*)(nk + 2048 + (size_t)tid * 8);
      kst2 = *(const short8*)(nk + 4096 + (size_t)tid * 8);
      kst3 = *(const short8*)(nk + 6144 + (size_t)tid * 8);
      vst0 = *(const short8*)(nv + (size_t)tid * 8);
      vst1 = *(const short8*)(nv + 2048 + (size_t)tid * 8);
      vst2 = *(const short8*)(nv + 4096 + (size_t)tid * 8);
      vst3 = *(const short8*)(nv + 6144 + (size_t)tid * 8);
    }
    // generic->LDS offset: low 32 bits of a shared-aperture address are the
    // LDS byte offset
    const unsigned vsbase = (unsigned)(size_t)&Vs[buf][0] + lane * 8;
#pragma unroll
    for (int si = 0; si < 4; ++si) {
      const int sub = sw + si;
      const unsigned short* kp = &Ks[buf][sub * 16 + col][0];
      short8 a0 = *(const short8*)&kp[quad * 8];
      short8 a1 = *(const short8*)&kp[32 + quad * 8];
      // V^T fragments for this sub, all 4 d-groups (issued early; latency
      // hides under the S^T MFMAs + exp2 below)
      short4v va0, va1, va2, va3;
      const unsigned vaddr = vsbase + sub * 2048;  // sub*1024 elems * 2B
      asm volatile("ds_read_b64_tr_b16 %0, %1" : "=v"(va0) : "v"(vaddr));
      asm volatile("ds_read_b64_tr_b16 %0, %1 offset:512" : "=v"(va1) : "v"(vaddr));
      asm volatile("ds_read_b64_tr_b16 %0, %1 offset:1024" : "=v"(va2) : "v"(vaddr));
      asm volatile("ds_read_b64_tr_b16 %0, %1 offset:1536" : "=v"(va3) : "v"(vaddr));
      short4v bb[4];
#pragma unroll
      for (int qg = 0; qg < 4; ++qg) {
        f32x4 s = {0.f, 0.f, 0.f, 0.f};
        s = __builtin_amdgcn_mfma_f32_16x16x32_bf16(a0, qbf[qg][0], s, 0, 0, 0);
        s = __builtin_amdgcn_mfma_f32_16x16x32_bf16(a1, qbf[qg][1], s, 0, 0, 0);
        const float p0 = __builtin_amdgcn_exp2f(s[0]);
        const float p1 = __builtin_amdgcn_exp2f(s[1]);
        const float p2 = __builtin_amdgcn_exp2f(s[2]);
        const float p3 = __builtin_amdgcn_exp2f(s[3]);
        zacc[qg] += (p0 + p1) + (p2 + p3);
        unsigned u01, u23;
        asm("v_cvt_pk_bf16_f32 %0, %1, %2" : "=v"(u01) : "v"(p0), "v"(p1));
        asm("v_cvt_pk_bf16_f32 %0, %1, %2" : "=v"(u23) : "v"(p2), "v"(p3));
        unsigned uu[2] = {u01, u23};
        __builtin_memcpy(&bb[qg], uu, 8);
      }
      asm volatile("s_waitcnt lgkmcnt(0)" ::: "memory");
      __builtin_amdgcn_sched_barrier(0);
#pragma unroll
      for (int qg = 0; qg < 4; ++qg) {
        MFMA16(Y[qg][0], va0, bb[qg]);
        MFMA16(Y[qg][1], va1, bb[qg]);
        MFMA16(Y[qg][2], va2, bb[qg]);
        MFMA16(Y[qg][3], va3, bb[qg]);
      }
    }
  }

  // ---- cross-wave z reduction ----
  // zacc[qg]: per-lane partial for l=(qw+qg)*16+col over keys
  // {sw..sw+4 subs} x {quad*4..+4} x 8 tiles. Quad-reduce -> wave partial
  // over its 512 keys; zred[wave][qg*16+col]; two waves per l (same qw,
  // different sw) sum to the full z.
#pragma unroll
  for (int qg = 0; qg < 4; ++qg) {
    float z = zacc[qg];
    z += __shfl_xor(z, 16, 64);
    z += __shfl_xor(z, 32, 64);
    if (quad == qg) zred[wave][qg * 16 + col] = z;
  }
  __syncthreads();
  float iz[4];
#pragma unroll
  for (int qg = 0; qg < 4; ++qg) {
    const float z = zred[wave & 6][qg * 16 + col] +
                    zred[(wave & 6) | 1][qg * 16 + col];
    iz[qg] = __builtin_amdgcn_rcpf(z);
  }
  asm volatile("s_nop 7\n\ts_nop 7");  // MFMA->VALU insurance
  // out_part[d] = sum over this wave's l-range of invz_l * Y_l[d];
  // Y lane layout: d = dg*16+quad*4+r, l = (qw+qg)*16+col.
#pragma unroll
  for (int dg = 0; dg < 4; ++dg)
#pragma unroll
    for (int r = 0; r < 4; ++r) {
      float v = Y[0][dg][r] * iz[0] + Y[1][dg][r] * iz[1] +
                Y[2][dg][r] * iz[2] + Y[3][dg][r] * iz[3];
      v += __shfl_xor(v, 1, 64);
      v += __shfl_xor(v, 2, 64);
      v += __shfl_xor(v, 4, 64);
      v += __shfl_xor(v, 8, 64);
      if (col == 0) red[wave][dg * 16 + quad * 4 + r] = v;
    }
  __syncthreads();
  if (tid < 64) {
    float p = red[0][tid] + red[1][tid] + red[2][tid] + red[3][tid];
    atomicAdd(&Oacc[(size_t)bh * 64 + tid], p);
  }
  if (tid == 0) {
    __threadfence();                      // release: O adds visible first
    lastFlag = (atomicAdd(&cnt[bh], 1) == 7);
  }
  __syncthreads();
  if (lastFlag && tid < 64) {
    __threadfence();                      // acquire
    float v = atomicAdd(&Oacc[(size_t)bh * 64 + tid], 0.f);
    float s = v;
#pragma unroll
    for (int off = 32; off >= 1; off >>= 1) s += __shfl_xor(s, off, 64);
    float mean = s * (1.f / 64.f);
    float diff = v - mean;
    float sq = diff * diff;
#pragma unroll
    for (int off = 32; off >= 1; off >>= 1) sq += __shfl_xor(sq, off, 64);
    float var = sq * (1.f / 64.f);
    float o = diff * rsqrtf(var + 1e-5f);
    const int b = bh >> 3, h = bh & 7;
    out[(size_t)b * 512 + h * 64 + tid] = o * gnw[h] + gnb[h];
  }
}

extern "C" void kernel_launch(void* const* d_in, const int* in_sizes, int n_in,
                              void* d_out, int out_size, void* d_ws,
                              size_t ws_size, hipStream_t stream) {
  (void)in_sizes; (void)n_in; (void)out_size; (void)ws_size;
  const float* emb  = (const float*)d_in[0];
  const float* W    = (const float*)d_in[1];
  const float* bias = (const float*)d_in[2];
  const float* gnw  = (const float*)d_in[3];
  const float* gnb  = (const float*)d_in[4];
  float* out = (float*)d_out;

  char* ws = (char*)d_ws;
  const size_t perQ = (size_t)BH * L_SEQ * DQ;        // 4,194,304 elems
  unsigned short* embB = (unsigned short*)ws;                      // 8 MB
  unsigned short* WB   = (unsigned short*)(ws + 8u * 1024 * 1024); // 1.5 MB
  unsigned short* Qb   = (unsigned short*)(ws + 10u * 1024 * 1024);
  unsigned short* Kb   = Qb + perQ;   // @18M
  unsigned short* Vb   = Kb + perQ;   // @26M
  float* Oacc = (float*)(ws + 35u * 1024 * 1024);     // 16 KB
  int*   cnt  = (int*)(ws + 35u * 1024 * 1024 + 64u * 1024);

  to_bf16<<<dim3(2432), 256, 0, stream>>>(emb, W, embB, WB, Oacc, cnt);
  qkv_mfma<<<dim3(768), 256, 0, stream>>>(embB, WB, bias, Qb, Kb, Vb);
  attn_one<<<dim3(512), 256, 0, stream>>>(Qb, Kb, Vb, gnw, gnb,
                                          Oacc, cnt, out);
}

// Round 12
// 126.387 us; speedup vs baseline: 1.0894x; 1.0894x over previous
//
#include <hip/hip_runtime.h>
#include <hip/hip_bf16.h>
#include <math.h>

#define L_SEQ 1024
#define BSZ 8
#define EMB 512
#define NH 8
#define DQ 64
#define BH 64          // BSZ*NH
#define NQKV 1536      // 3*NH*DQ

// Q is pre-scaled by (emb_dim/n_head)^-0.5 * log2(e) so that
// softmax numerator = exp2(mfma_score) with zero extra VALU per element.
#define SCALE_Q 0.18033688f

typedef __attribute__((ext_vector_type(8))) short short8;   // 8 bf16 = 4 VGPR
typedef __attribute__((ext_vector_type(4))) short short4v;  // 4 bf16 = 2 VGPR
typedef __attribute__((ext_vector_type(4))) float f32x4;

#define GPTR(x) ((const __attribute__((address_space(1))) void*)(x))
#define LPTR(x) ((__attribute__((address_space(3))) void*)(x))

// PV matmul: 16x16x16 bf16 MFMA. B-fragment layout (k = quad*4+e) matches
// the S^T C-layout natively -> no cross-lane shuffles needed for P.
#if __has_builtin(__builtin_amdgcn_mfma_f32_16x16x16bf16_1k)
#define MFMA16(acc, a, b) \
  acc = __builtin_amdgcn_mfma_f32_16x16x16bf16_1k(a, b, acc, 0, 0, 0)
#else
#define MFMA16(acc, a, b) \
  asm volatile("v_mfma_f32_16x16x16_bf16 %0, %1, %2, %0" \
               : "+v"(acc) : "v"(a), "v"(b))
#endif

__device__ __forceinline__ unsigned short bf16u(float x) {
  __hip_bfloat16 h = __float2bfloat16(x);
  return *(unsigned short*)&h;
}

// ---------------------------------------------------------------------------
// Kernel 0: f32 -> bf16 convert of emb (8192x512) and W (1536x512).
// Block 0 also zero-inits Oacc/cnt (stream order guarantees init before
// attn_one's blocks race on cnt).
// ---------------------------------------------------------------------------
__global__ __launch_bounds__(256) void to_bf16(
    const float* __restrict__ emb, const float* __restrict__ W,
    unsigned short* __restrict__ embB, unsigned short* __restrict__ WB,
    float* __restrict__ Oacc, int* __restrict__ cnt) {
  const int tid = threadIdx.x;
  if (blockIdx.x == 0) {
    for (int i = tid; i < BH * DQ; i += 256) Oacc[i] = 0.f;
    if (tid < BH) cnt[tid] = 0;
  }
  const size_t t = (size_t)blockIdx.x * 256 + tid;
  size_t base = t * 8;
  const float* src;
  unsigned short* dst;
  size_t off;
  if (base < (size_t)8192 * 512) { src = emb; dst = embB; off = base; }
  else { src = W; dst = WB; off = base - (size_t)8192 * 512; }
  float4 v0 = *(const float4*)&src[off];
  float4 v1 = *(const float4*)&src[off + 4];
  short8 o;
  o[0] = bf16u(v0.x); o[1] = bf16u(v0.y); o[2] = bf16u(v0.z); o[3] = bf16u(v0.w);
  o[4] = bf16u(v1.x); o[5] = bf16u(v1.y); o[6] = bf16u(v1.z); o[7] = bf16u(v1.w);
  *(short8*)&dst[off] = o;
}

// ---------------------------------------------------------------------------
// Kernel A: QKV projection, bf16 MFMA (m97 pattern). Q gets SCALE_Q folded in.
// (round-5 version, verbatim: two-pass epilogue, 33 KB LDS, XCD swizzle)
// ---------------------------------------------------------------------------
__global__ __launch_bounds__(256, 4) void qkv_mfma(
    const unsigned short* __restrict__ A,   // embB [8192][512]
    const unsigned short* __restrict__ B,   // WB   [1536][512]
    const float* __restrict__ bias,
    unsigned short* __restrict__ Qb, unsigned short* __restrict__ Kb,
    unsigned short* __restrict__ Vb) {
  __shared__ __align__(16) unsigned short As[128][32];  // 8 KB, unpadded
  __shared__ __align__(16) unsigned short Bs[128][32];  // 8 KB
  __shared__ __align__(16) unsigned short Cs[128][68];  // 17 KB, +4 pad
  const int tid = threadIdx.x;
  const int wave = tid >> 6, lane = tid & 63;
  const int quad = lane >> 4, col = lane & 15;
  const int wr = wave >> 1, wc = wave & 1;
  const int id = blockIdx.x;
  const int sid = (id & 7) * 96 + (id >> 3);
  const int mb = sid / 12, nb = sid - mb * 12;
  const int m0 = mb * 128, n0 = nb * 128;
  const int r16 = lane >> 2, q4 = lane & 3;

  f32x4 acc[4][4] = {};

  for (int kt = 0; kt < EMB; kt += 32) {
    __syncthreads();
#pragma unroll
    for (int c = 0; c < 2; ++c) {
      const int rowA = (c * 4 + wave) * 16;
      __builtin_amdgcn_global_load_lds(
          GPTR(A + (size_t)(m0 + rowA + r16) * EMB + kt + q4 * 8),
          LPTR(&As[rowA][0]), 16, 0, 0);
      __builtin_amdgcn_global_load_lds(
          GPTR(B + (size_t)(n0 + rowA + r16) * EMB + kt + q4 * 8),
          LPTR(&Bs[rowA][0]), 16, 0, 0);
    }
    __syncthreads();
    short8 af[4], bf[4];
#pragma unroll
    for (int i = 0; i < 4; ++i)
      af[i] = *(const short8*)&As[wr * 64 + i * 16 + col][quad * 8];
#pragma unroll
    for (int j = 0; j < 4; ++j)
      bf[j] = *(const short8*)&Bs[wc * 64 + j * 16 + col][quad * 8];
#pragma unroll
    for (int i = 0; i < 4; ++i)
#pragma unroll
      for (int j = 0; j < 4; ++j)
        acc[i][j] =
            __builtin_amdgcn_mfma_f32_16x16x32_bf16(af[i], bf[j], acc[i][j],
                                                    0, 0, 0);
  }

  const int bb = lane >> 3, oct = lane & 7;
#pragma unroll
  for (int h = 0; h < 2; ++h) {
    __syncthreads();
    if (wc == h) {
#pragma unroll
      for (int j = 0; j < 4; ++j) {
        const int n = j * 16 + col;
        const float bj = bias[n0 + h * 64 + n];
        const bool isQ = (((n0 + h * 64 + n) >> 6) % 3) == 0;
#pragma unroll
        for (int i = 0; i < 4; ++i) {
          const int mrow = wr * 64 + i * 16 + quad * 4;
#pragma unroll
          for (int r = 0; r < 4; ++r) {
            float val = acc[i][j][r] + bj;
            if (isQ) val *= SCALE_Q;
            Cs[mrow + r][n] = bf16u(val);
          }
        }
      }
    }
    __syncthreads();
    const int G = (n0 >> 6) + h;
    const int hd = G / 3, sel = G % 3;
    unsigned short* dst = (sel == 0) ? Qb : (sel == 1) ? Kb : Vb;
#pragma unroll
    for (int e = 0; e < 4; ++e) {
      const int l = wave * 4 + e;
      short8 v = *(const short8*)&Cs[l * 8 + bb][oct * 8];
      const int lglob = (m0 >> 3) + l;
      *(short8*)&dst[(((size_t)(bb * NH + hd)) * L_SEQ + lglob) * DQ + oct * 8] = v;
    }
  }
}

// ---------------------------------------------------------------------------
// Kernel B (v15): single-sweep attention = R10's v13 partition VERBATIM
// (R11's quadrant repartition regressed 45%/wave at identical work — same-
// work repartitions consistently lose; only work reductions won). One
// addition: T5 s_setprio(1)/(0) around each sub's compute cluster
// (MFMA32+exp2+cvt+MFMA16). Prior: m191 attn +4-7% when co-resident waves
// sit at different phases — our 2 independent blocks/CU provide the role
// split (compute-wave preempts the other block's staging/stall waves).
// ---------------------------------------------------------------------------
__global__ __launch_bounds__(256) void attn_one(
    const unsigned short* __restrict__ Qb, const unsigned short* __restrict__ Kb,
    const unsigned short* __restrict__ Vb,
    const float* __restrict__ gnw, const float* __restrict__ gnb,
    float* __restrict__ Oacc, int* __restrict__ cnt, float* __restrict__ out) {
  const int bh = blockIdx.x & 63;   // blk%8 = bh%8 -> same-bh blocks same XCD
  const int qc = blockIdx.x >> 6;   // 0..7, 128 q-rows each
  const int tid = threadIdx.x;
  const int wave = tid >> 6, lane = tid & 63;
  const int quad = lane >> 4, col = lane & 15;

  __shared__ __align__(16) unsigned short Ks[2][128][72];  // 36864 B
  __shared__ __align__(16) unsigned short Vs[2][8192];     // 32768 B subtiled
  __shared__ float red[4][64];
  __shared__ int lastFlag;

  const unsigned short* kbase = &Kb[(size_t)bh * L_SEQ * DQ];
  const unsigned short* vbase = &Vb[(size_t)bh * L_SEQ * DQ];

  // Q as B-operand fragments (q = qg*16+col, depth 64 in two halves)
  short8 qbf[2][2];
#pragma unroll
  for (int qg = 0; qg < 2; ++qg) {
    const unsigned short* qp =
        &Qb[((size_t)bh * L_SEQ + qc * 128 + wave * 32 + qg * 16 + col) * DQ];
    qbf[qg][0] = *(const short8*)&qp[quad * 8];
    qbf[qg][1] = *(const short8*)&qp[32 + quad * 8];
  }

  const int srow = tid >> 3;        // staging row 0..31 (+32*chunk)
  const int scol = (tid & 7) * 8;   // staging col (shorts)

  float zacc[2] = {0.f, 0.f};
  f32x4 Y[2][4] = {};               // [qg][dg]

  // V subtile store offsets: elem (k,d) -> ((k>>4)*4 + (d>>4))*256
  //                                        + (k&15)*16 + (d&15)
  int voff[4];
#pragma unroll
  for (int c = 0; c < 4; ++c) {
    const int kdx = c * 32 + srow;
    voff[c] = ((kdx >> 4) * 4 + (scol >> 4)) * 256 + (kdx & 15) * 16 + (scol & 15);
  }

  short8 kst0, kst1, kst2, kst3, vst0, vst1, vst2, vst3;
  {  // prefetch tile 0 (K and V tiles are 16 KB contiguous)
    kst0 = *(const short8*)(kbase + (size_t)tid * 8);
    kst1 = *(const short8*)(kbase + 2048 + (size_t)tid * 8);
    kst2 = *(const short8*)(kbase + 4096 + (size_t)tid * 8);
    kst3 = *(const short8*)(kbase + 6144 + (size_t)tid * 8);
    vst0 = *(const short8*)(vbase + (size_t)tid * 8);
    vst1 = *(const short8*)(vbase + 2048 + (size_t)tid * 8);
    vst2 = *(const short8*)(vbase + 4096 + (size_t)tid * 8);
    vst3 = *(const short8*)(vbase + 6144 + (size_t)tid * 8);
  }

  for (int kt = 0; kt < 8; ++kt) {
    const int buf = kt & 1;
    *(short8*)&Ks[buf][srow][scol] = kst0;
    *(short8*)&Ks[buf][32 + srow][scol] = kst1;
    *(short8*)&Ks[buf][64 + srow][scol] = kst2;
    *(short8*)&Ks[buf][96 + srow][scol] = kst3;
    *(short8*)&Vs[buf][voff[0]] = vst0;
    *(short8*)&Vs[buf][voff[1]] = vst1;
    *(short8*)&Vs[buf][voff[2]] = vst2;
    *(short8*)&Vs[buf][voff[3]] = vst3;
    __syncthreads();
    if (kt + 1 < 8) {  // post-barrier prefetch: in flight through compute
      const unsigned short* nk = kbase + (size_t)(kt + 1) * 8192;
      const unsigned short* nv = vbase + (size_t)(kt + 1) * 8192;
      kst0 = *(const short8*)(nk + (size_t)tid * 8);
      kst1 = *(const short8*)(nk + 2048 + (size_t)tid * 8);
      kst2 = *(const short8*)(nk + 4096 + (size_t)tid * 8);
      kst3 = *(const short8*)(nk + 6144 + (size_t)tid * 8);
      vst0 = *(const short8*)(nv + (size_t)tid * 8);
      vst1 = *(const short8*)(nv + 2048 + (size_t)tid * 8);
      vst2 = *(const short8*)(nv + 4096 + (size_t)tid * 8);
      vst3 = *(const short8*)(nv + 6144 + (size_t)tid * 8);
    }
    // generic->LDS offset: low 32 bits of a shared-aperture address are the
    // LDS byte offset
    const unsigned vsbase = (unsigned)(size_t)&Vs[buf][0] + lane * 8;
#pragma unroll
    for (int sub = 0; sub < 8; ++sub) {
      const unsigned short* kp = &Ks[buf][sub * 16 + col][0];
      short8 a0 = *(const short8*)&kp[quad * 8];
      short8 a1 = *(const short8*)&kp[32 + quad * 8];
      // V^T fragments for this 16-key sub, all 4 d-groups (issued early;
      // latency hides under the S^T MFMAs + exp2 below)
      short4v va0, va1, va2, va3;
      const unsigned vaddr = vsbase + sub * 2048;  // sub*1024 elems * 2B
      asm volatile("ds_read_b64_tr_b16 %0, %1" : "=v"(va0) : "v"(vaddr));
      asm volatile("ds_read_b64_tr_b16 %0, %1 offset:512" : "=v"(va1) : "v"(vaddr));
      asm volatile("ds_read_b64_tr_b16 %0, %1 offset:1024" : "=v"(va2) : "v"(vaddr));
      asm volatile("ds_read_b64_tr_b16 %0, %1 offset:1536" : "=v"(va3) : "v"(vaddr));
      __builtin_amdgcn_s_setprio(1);   // T5: favor compute cluster (m191)
      short4v bb[2];
#pragma unroll
      for (int qg = 0; qg < 2; ++qg) {
        f32x4 s = {0.f, 0.f, 0.f, 0.f};
        s = __builtin_amdgcn_mfma_f32_16x16x32_bf16(a0, qbf[qg][0], s, 0, 0, 0);
        s = __builtin_amdgcn_mfma_f32_16x16x32_bf16(a1, qbf[qg][1], s, 0, 0, 0);
        const float p0 = __builtin_amdgcn_exp2f(s[0]);
        const float p1 = __builtin_amdgcn_exp2f(s[1]);
        const float p2 = __builtin_amdgcn_exp2f(s[2]);
        const float p3 = __builtin_amdgcn_exp2f(s[3]);
        zacc[qg] += (p0 + p1) + (p2 + p3);
        unsigned u01, u23;
        asm("v_cvt_pk_bf16_f32 %0, %1, %2" : "=v"(u01) : "v"(p0), "v"(p1));
        asm("v_cvt_pk_bf16_f32 %0, %1, %2" : "=v"(u23) : "v"(p2), "v"(p3));
        unsigned uu[2] = {u01, u23};
        __builtin_memcpy(&bb[qg], uu, 8);
      }
      asm volatile("s_waitcnt lgkmcnt(0)" ::: "memory");
      __builtin_amdgcn_sched_barrier(0);
#pragma unroll
      for (int qg = 0; qg < 2; ++qg) {
        MFMA16(Y[qg][0], va0, bb[qg]);
        MFMA16(Y[qg][1], va1, bb[qg]);
        MFMA16(Y[qg][2], va2, bb[qg]);
        MFMA16(Y[qg][3], va3, bb[qg]);
      }
      __builtin_amdgcn_s_setprio(0);
    }
  }

  // z: reduce over quads (lanes same col, different quad hold disjoint keys)
  float iz0, iz1;
  {
    float z0 = zacc[0];
    z0 += __shfl_xor(z0, 16, 64);
    z0 += __shfl_xor(z0, 32, 64);
    iz0 = __builtin_amdgcn_rcpf(z0);
    float z1 = zacc[1];
    z1 += __shfl_xor(z1, 16, 64);
    z1 += __shfl_xor(z1, 32, 64);
    iz1 = __builtin_amdgcn_rcpf(z1);
  }
  asm volatile("s_nop 7\n\ts_nop 7");  // MFMA->VALU insurance (asm fallback)
  // out_part[d] = sum_q invz[q] * Y[d][q]; Y lane layout: d = dg*16+quad*4+r,
  // q = col. Scale, sum both q-groups, reduce over the 16 col-lanes.
#pragma unroll
  for (int dg = 0; dg < 4; ++dg)
#pragma unroll
    for (int r = 0; r < 4; ++r) {
      float v = Y[0][dg][r] * iz0 + Y[1][dg][r] * iz1;
      v += __shfl_xor(v, 1, 64);
      v += __shfl_xor(v, 2, 64);
      v += __shfl_xor(v, 4, 64);
      v += __shfl_xor(v, 8, 64);
      if (col == 0) red[wave][dg * 16 + quad * 4 + r] = v;
    }
  __syncthreads();
  if (tid < 64) {
    float p = red[0][tid] + red[1][tid] + red[2][tid] + red[3][tid];
    atomicAdd(&Oacc[(size_t)bh * 64 + tid], p);
  }
  if (tid == 0) {
    __threadfence();                      // release: O adds visible first
    lastFlag = (atomicAdd(&cnt[bh], 1) == 7);
  }
  __syncthreads();
  if (lastFlag && tid < 64) {
    __threadfence();                      // acquire
    float v = atomicAdd(&Oacc[(size_t)bh * 64 + tid], 0.f);
    float s = v;
#pragma unroll
    for (int off = 32; off >= 1; off >>= 1) s += __shfl_xor(s, off, 64);
    float mean = s * (1.f / 64.f);
    float diff = v - mean;
    float sq = diff * diff;
#pragma unroll
    for (int off = 32; off >= 1; off >>= 1) sq += __shfl_xor(sq, off, 64);
    float var = sq * (1.f / 64.f);
    float o = diff * rsqrtf(var + 1e-5f);
    const int b = bh >> 3, h = bh & 7;
    out[(size_t)b * 512 + h * 64 + tid] = o * gnw[h] + gnb[h];
  }
}

extern "C" void kernel_launch(void* const* d_in, const int* in_sizes, int n_in,
                              void* d_out, int out_size, void* d_ws,
                              size_t ws_size, hipStream_t stream) {
  (void)in_sizes; (void)n_in; (void)out_size; (void)ws_size;
  const float* emb  = (const float*)d_in[0];
  const float* W    = (const float*)d_in[1];
  const float* bias = (const float*)d_in[2];
  const float* gnw  = (const float*)d_in[3];
  const float* gnb  = (const float*)d_in[4];
  float* out = (float*)d_out;

  char* ws = (char*)d_ws;
  const size_t perQ = (size_t)BH * L_SEQ * DQ;        // 4,194,304 elems
  unsigned short* embB = (unsigned short*)ws;                      // 8 MB
  unsigned short* WB   = (unsigned short*)(ws + 8u * 1024 * 1024); // 1.5 MB
  unsigned short* Qb   = (unsigned short*)(ws + 10u * 1024 * 1024);
  unsigned short* Kb   = Qb + perQ;   // @18M
  unsigned short* Vb   = Kb + perQ;   // @26M
  float* Oacc = (float*)(ws + 35u * 1024 * 1024);     // 16 KB
  int*   cnt  = (int*)(ws + 35u * 1024 * 1024 + 64u * 1024);

  to_bf16<<<dim3(2432), 256, 0, stream>>>(emb, W, embB, WB, Oacc, cnt);
  qkv_mfma<<<dim3(768), 256, 0, stream>>>(embB, WB, bias, Qb, Kb, Vb);
  attn_one<<<dim3(512), 256, 0, stream>>>(Qb, Kb, Vb, gnw, gnb,
                                          Oacc, cnt, out);
}

// Round 14
// 126.287 us; speedup vs baseline: 1.0903x; 1.0008x over previous
//
#include <hip/hip_runtime.h>
#include <hip/hip_bf16.h>
#include <math.h>

#define L_SEQ 1024
#define BSZ 8
#define EMB 512
#define NH 8
#define DQ 64
#define BH 64          // BSZ*NH
#define NQKV 1536      // 3*NH*DQ

// Q is pre-scaled by (emb_dim/n_head)^-0.5 * log2(e) so that
// softmax numerator = exp2(mfma_score) with zero extra VALU per element.
#define SCALE_Q 0.18033688f

typedef __attribute__((ext_vector_type(8))) short short8;   // 8 bf16 = 4 VGPR
typedef __attribute__((ext_vector_type(4))) short short4v;  // 4 bf16 = 2 VGPR
typedef __attribute__((ext_vector_type(4))) float f32x4;

#define GPTR(x) ((const __attribute__((address_space(1))) void*)(x))
#define LPTR(x) ((__attribute__((address_space(3))) void*)(x))

// PV matmul: 16x16x16 bf16 MFMA. B-fragment layout (k = quad*4+e) matches
// the S^T C-layout natively -> no cross-lane shuffles needed for P.
#if __has_builtin(__builtin_amdgcn_mfma_f32_16x16x16bf16_1k)
#define MFMA16(acc, a, b) \
  acc = __builtin_amdgcn_mfma_f32_16x16x16bf16_1k(a, b, acc, 0, 0, 0)
#else
#define MFMA16(acc, a, b) \
  asm volatile("v_mfma_f32_16x16x16_bf16 %0, %1, %2, %0" \
               : "+v"(acc) : "v"(a), "v"(b))
#endif

__device__ __forceinline__ unsigned short bf16u(float x) {
  __hip_bfloat16 h = __float2bfloat16(x);
  return *(unsigned short*)&h;
}

// ---------------------------------------------------------------------------
// Kernel 0: f32 -> bf16 convert of emb (8192x512) and W (1536x512).
// Block 0 also zero-inits Oacc/cnt (stream order guarantees init before
// attn_one's blocks race on cnt).
// ---------------------------------------------------------------------------
__global__ __launch_bounds__(256) void to_bf16(
    const float* __restrict__ emb, const float* __restrict__ W,
    unsigned short* __restrict__ embB, unsigned short* __restrict__ WB,
    float* __restrict__ Oacc, int* __restrict__ cnt) {
  const int tid = threadIdx.x;
  if (blockIdx.x == 0) {
    for (int i = tid; i < BH * DQ; i += 256) Oacc[i] = 0.f;
    if (tid < BH) cnt[tid] = 0;
  }
  const size_t t = (size_t)blockIdx.x * 256 + tid;
  size_t base = t * 8;
  const float* src;
  unsigned short* dst;
  size_t off;
  if (base < (size_t)8192 * 512) { src = emb; dst = embB; off = base; }
  else { src = W; dst = WB; off = base - (size_t)8192 * 512; }
  float4 v0 = *(const float4*)&src[off];
  float4 v1 = *(const float4*)&src[off + 4];
  short8 o;
  o[0] = bf16u(v0.x); o[1] = bf16u(v0.y); o[2] = bf16u(v0.z); o[3] = bf16u(v0.w);
  o[4] = bf16u(v1.x); o[5] = bf16u(v1.y); o[6] = bf16u(v1.z); o[7] = bf16u(v1.w);
  *(short8*)&dst[off] = o;
}

// ---------------------------------------------------------------------------
// Kernel A: QKV projection, bf16 MFMA (m97 pattern). Q gets SCALE_Q folded in.
// (round-5 version, verbatim: two-pass epilogue, 33 KB LDS, XCD swizzle)
// ---------------------------------------------------------------------------
__global__ __launch_bounds__(256, 4) void qkv_mfma(
    const unsigned short* __restrict__ A,   // embB [8192][512]
    const unsigned short* __restrict__ B,   // WB   [1536][512]
    const float* __restrict__ bias,
    unsigned short* __restrict__ Qb, unsigned short* __restrict__ Kb,
    unsigned short* __restrict__ Vb) {
  __shared__ __align__(16) unsigned short As[128][32];  // 8 KB, unpadded
  __shared__ __align__(16) unsigned short Bs[128][32];  // 8 KB
  __shared__ __align__(16) unsigned short Cs[128][68];  // 17 KB, +4 pad
  const int tid = threadIdx.x;
  const int wave = tid >> 6, lane = tid & 63;
  const int quad = lane >> 4, col = lane & 15;
  const int wr = wave >> 1, wc = wave & 1;
  const int id = blockIdx.x;
  const int sid = (id & 7) * 96 + (id >> 3);
  const int mb = sid / 12, nb = sid - mb * 12;
  const int m0 = mb * 128, n0 = nb * 128;
  const int r16 = lane >> 2, q4 = lane & 3;

  f32x4 acc[4][4] = {};

  for (int kt = 0; kt < EMB; kt += 32) {
    __syncthreads();
#pragma unroll
    for (int c = 0; c < 2; ++c) {
      const int rowA = (c * 4 + wave) * 16;
      __builtin_amdgcn_global_load_lds(
          GPTR(A + (size_t)(m0 + rowA + r16) * EMB + kt + q4 * 8),
          LPTR(&As[rowA][0]), 16, 0, 0);
      __builtin_amdgcn_global_load_lds(
          GPTR(B + (size_t)(n0 + rowA + r16) * EMB + kt + q4 * 8),
          LPTR(&Bs[rowA][0]), 16, 0, 0);
    }
    __syncthreads();
    short8 af[4], bf[4];
#pragma unroll
    for (int i = 0; i < 4; ++i)
      af[i] = *(const short8*)&As[wr * 64 + i * 16 + col][quad * 8];
#pragma unroll
    for (int j = 0; j < 4; ++j)
      bf[j] = *(const short8*)&Bs[wc * 64 + j * 16 + col][quad * 8];
#pragma unroll
    for (int i = 0; i < 4; ++i)
#pragma unroll
      for (int j = 0; j < 4; ++j)
        acc[i][j] =
            __builtin_amdgcn_mfma_f32_16x16x32_bf16(af[i], bf[j], acc[i][j],
                                                    0, 0, 0);
  }

  const int bb = lane >> 3, oct = lane & 7;
#pragma unroll
  for (int h = 0; h < 2; ++h) {
    __syncthreads();
    if (wc == h) {
#pragma unroll
      for (int j = 0; j < 4; ++j) {
        const int n = j * 16 + col;
        const float bj = bias[n0 + h * 64 + n];
        const bool isQ = (((n0 + h * 64 + n) >> 6) % 3) == 0;
#pragma unroll
        for (int i = 0; i < 4; ++i) {
          const int mrow = wr * 64 + i * 16 + quad * 4;
#pragma unroll
          for (int r = 0; r < 4; ++r) {
            float val = acc[i][j][r] + bj;
            if (isQ) val *= SCALE_Q;
            Cs[mrow + r][n] = bf16u(val);
          }
        }
      }
    }
    __syncthreads();
    const int G = (n0 >> 6) + h;
    const int hd = G / 3, sel = G % 3;
    unsigned short* dst = (sel == 0) ? Qb : (sel == 1) ? Kb : Vb;
#pragma unroll
    for (int e = 0; e < 4; ++e) {
      const int l = wave * 4 + e;
      short8 v = *(const short8*)&Cs[l * 8 + bb][oct * 8];
      const int lglob = (m0 >> 3) + l;
      *(short8*)&dst[(((size_t)(bb * NH + hd)) * L_SEQ + lglob) * DQ + oct * 8] = v;
    }
  }
}

// ---------------------------------------------------------------------------
// Kernel B (v15 = R12 verbatim, the session-best verified version):
// single-sweep attention, R10 partition, per-sub lgkmcnt(0)+sched_barrier
// fence (the PROVEN pattern; R13's batched-fence variant NaN'd via a
// compiler-level interaction of 24 outstanding LDS ops under one manual
// fence), T5 setprio around each sub's compute cluster.
// ---------------------------------------------------------------------------
__global__ __launch_bounds__(256) void attn_one(
    const unsigned short* __restrict__ Qb, const unsigned short* __restrict__ Kb,
    const unsigned short* __restrict__ Vb,
    const float* __restrict__ gnw, const float* __restrict__ gnb,
    float* __restrict__ Oacc, int* __restrict__ cnt, float* __restrict__ out) {
  const int bh = blockIdx.x & 63;   // blk%8 = bh%8 -> same-bh blocks same XCD
  const int qc = blockIdx.x >> 6;   // 0..7, 128 q-rows each
  const int tid = threadIdx.x;
  const int wave = tid >> 6, lane = tid & 63;
  const int quad = lane >> 4, col = lane & 15;

  __shared__ __align__(16) unsigned short Ks[2][128][72];  // 36864 B
  __shared__ __align__(16) unsigned short Vs[2][8192];     // 32768 B subtiled
  __shared__ float red[4][64];
  __shared__ int lastFlag;

  const unsigned short* kbase = &Kb[(size_t)bh * L_SEQ * DQ];
  const unsigned short* vbase = &Vb[(size_t)bh * L_SEQ * DQ];

  // Q as B-operand fragments (q = qg*16+col, depth 64 in two halves)
  short8 qbf[2][2];
#pragma unroll
  for (int qg = 0; qg < 2; ++qg) {
    const unsigned short* qp =
        &Qb[((size_t)bh * L_SEQ + qc * 128 + wave * 32 + qg * 16 + col) * DQ];
    qbf[qg][0] = *(const short8*)&qp[quad * 8];
    qbf[qg][1] = *(const short8*)&qp[32 + quad * 8];
  }

  const int srow = tid >> 3;        // staging row 0..31 (+32*chunk)
  const int scol = (tid & 7) * 8;   // staging col (shorts)

  float zacc[2] = {0.f, 0.f};
  f32x4 Y[2][4] = {};               // [qg][dg]

  // V subtile store offsets: elem (k,d) -> ((k>>4)*4 + (d>>4))*256
  //                                        + (k&15)*16 + (d&15)
  int voff[4];
#pragma unroll
  for (int c = 0; c < 4; ++c) {
    const int kdx = c * 32 + srow;
    voff[c] = ((kdx >> 4) * 4 + (scol >> 4)) * 256 + (kdx & 15) * 16 + (scol & 15);
  }

  short8 kst0, kst1, kst2, kst3, vst0, vst1, vst2, vst3;
  {  // prefetch tile 0 (K and V tiles are 16 KB contiguous)
    kst0 = *(const short8*)(kbase + (size_t)tid * 8);
    kst1 = *(const short8*)(kbase + 2048 + (size_t)tid * 8);
    kst2 = *(const short8*)(kbase + 4096 + (size_t)tid * 8);
    kst3 = *(const short8*)(kbase + 6144 + (size_t)tid * 8);
    vst0 = *(const short8*)(vbase + (size_t)tid * 8);
    vst1 = *(const short8*)(vbase + 2048 + (size_t)tid * 8);
    vst2 = *(const short8*)(vbase + 4096 + (size_t)tid * 8);
    vst3 = *(const short8*)(vbase + 6144 + (size_t)tid * 8);
  }

  for (int kt = 0; kt < 8; ++kt) {
    const int buf = kt & 1;
    *(short8*)&Ks[buf][srow][scol] = kst0;
    *(short8*)&Ks[buf][32 + srow][scol] = kst1;
    *(short8*)&Ks[buf][64 + srow][scol] = kst2;
    *(short8*)&Ks[buf][96 + srow][scol] = kst3;
    *(short8*)&Vs[buf][voff[0]] = vst0;
    *(short8*)&Vs[buf][voff[1]] = vst1;
    *(short8*)&Vs[buf][voff[2]] = vst2;
    *(short8*)&Vs[buf][voff[3]] = vst3;
    __syncthreads();
    if (kt + 1 < 8) {  // post-barrier prefetch: in flight through compute
      const unsigned short* nk = kbase + (size_t)(kt + 1) * 8192;
      const unsigned short* nv = vbase + (size_t)(kt + 1) * 8192;
      kst0 = *(const short8*)(nk + (size_t)tid * 8);
      kst1 = *(const short8*)(nk + 2048 + (size_t)tid * 8);
      kst2 = *(const short8*)(nk + 4096 + (size_t)tid * 8);
      kst3 = *(const short8*)(nk + 6144 + (size_t)tid * 8);
      vst0 = *(const short8*)(nv + (size_t)tid * 8);
      vst1 = *(const short8*)(nv + 2048 + (size_t)tid * 8);
      vst2 = *(const short8*)(nv + 4096 + (size_t)tid * 8);
      vst3 = *(const short8*)(nv + 6144 + (size_t)tid * 8);
    }
    // generic->LDS offset: low 32 bits of a shared-aperture address are the
    // LDS byte offset
    const unsigned vsbase = (unsigned)(size_t)&Vs[buf][0] + lane * 8;
#pragma unroll
    for (int sub = 0; sub < 8; ++sub) {
      const unsigned short* kp = &Ks[buf][sub * 16 + col][0];
      short8 a0 = *(const short8*)&kp[quad * 8];
      short8 a1 = *(const short8*)&kp[32 + quad * 8];
      // V^T fragments for this 16-key sub, all 4 d-groups (issued early;
      // latency hides under the S^T MFMAs + exp2 below)
      short4v va0, va1, va2, va3;
      const unsigned vaddr = vsbase + sub * 2048;  // sub*1024 elems * 2B
      asm volatile("ds_read_b64_tr_b16 %0, %1" : "=v"(va0) : "v"(vaddr));
      asm volatile("ds_read_b64_tr_b16 %0, %1 offset:512" : "=v"(va1) : "v"(vaddr));
      asm volatile("ds_read_b64_tr_b16 %0, %1 offset:1024" : "=v"(va2) : "v"(vaddr));
      asm volatile("ds_read_b64_tr_b16 %0, %1 offset:1536" : "=v"(va3) : "v"(vaddr));
      __builtin_amdgcn_s_setprio(1);   // T5: favor compute cluster (m191)
      short4v bb[2];
#pragma unroll
      for (int qg = 0; qg < 2; ++qg) {
        f32x4 s = {0.f, 0.f, 0.f, 0.f};
        s = __builtin_amdgcn_mfma_f32_16x16x32_bf16(a0, qbf[qg][0], s, 0, 0, 0);
        s = __builtin_amdgcn_mfma_f32_16x16x32_bf16(a1, qbf[qg][1], s, 0, 0, 0);
        const float p0 = __builtin_amdgcn_exp2f(s[0]);
        const float p1 = __builtin_amdgcn_exp2f(s[1]);
        const float p2 = __builtin_amdgcn_exp2f(s[2]);
        const float p3 = __builtin_amdgcn_exp2f(s[3]);
        zacc[qg] += (p0 + p1) + (p2 + p3);
        unsigned u01, u23;
        asm("v_cvt_pk_bf16_f32 %0, %1, %2" : "=v"(u01) : "v"(p0), "v"(p1));
        asm("v_cvt_pk_bf16_f32 %0, %1, %2" : "=v"(u23) : "v"(p2), "v"(p3));
        unsigned uu[2] = {u01, u23};
        __builtin_memcpy(&bb[qg], uu, 8);
      }
      asm volatile("s_waitcnt lgkmcnt(0)" ::: "memory");
      __builtin_amdgcn_sched_barrier(0);
#pragma unroll
      for (int qg = 0; qg < 2; ++qg) {
        MFMA16(Y[qg][0], va0, bb[qg]);
        MFMA16(Y[qg][1], va1, bb[qg]);
        MFMA16(Y[qg][2], va2, bb[qg]);
        MFMA16(Y[qg][3], va3, bb[qg]);
      }
      __builtin_amdgcn_s_setprio(0);
    }
  }

  // z: reduce over quads (lanes same col, different quad hold disjoint keys)
  float iz0, iz1;
  {
    float z0 = zacc[0];
    z0 += __shfl_xor(z0, 16, 64);
    z0 += __shfl_xor(z0, 32, 64);
    iz0 = __builtin_amdgcn_rcpf(z0);
    float z1 = zacc[1];
    z1 += __shfl_xor(z1, 16, 64);
    z1 += __shfl_xor(z1, 32, 64);
    iz1 = __builtin_amdgcn_rcpf(z1);
  }
  asm volatile("s_nop 7\n\ts_nop 7");  // MFMA->VALU insurance (asm fallback)
  // out_part[d] = sum_q invz[q] * Y[d][q]; Y lane layout: d = dg*16+quad*4+r,
  // q = col. Scale, sum both q-groups, reduce over the 16 col-lanes.
#pragma unroll
  for (int dg = 0; dg < 4; ++dg)
#pragma unroll
    for (int r = 0; r < 4; ++r) {
      float v = Y[0][dg][r] * iz0 + Y[1][dg][r] * iz1;
      v += __shfl_xor(v, 1, 64);
      v += __shfl_xor(v, 2, 64);
      v += __shfl_xor(v, 4, 64);
      v += __shfl_xor(v, 8, 64);
      if (col == 0) red[wave][dg * 16 + quad * 4 + r] = v;
    }
  __syncthreads();
  if (tid < 64) {
    float p = red[0][tid] + red[1][tid] + red[2][tid] + red[3][tid];
    atomicAdd(&Oacc[(size_t)bh * 64 + tid], p);
  }
  if (tid == 0) {
    __threadfence();                      // release: O adds visible first
    lastFlag = (atomicAdd(&cnt[bh], 1) == 7);
  }
  __syncthreads();
  if (lastFlag && tid < 64) {
    __threadfence();                      // acquire
    float v = atomicAdd(&Oacc[(size_t)bh * 64 + tid], 0.f);
    float s = v;
#pragma unroll
    for (int off = 32; off >= 1; off >>= 1) s += __shfl_xor(s, off, 64);
    float mean = s * (1.f / 64.f);
    float diff = v - mean;
    float sq = diff * diff;
#pragma unroll
    for (int off = 32; off >= 1; off >>= 1) sq += __shfl_xor(sq, off, 64);
    float var = sq * (1.f / 64.f);
    float o = diff * rsqrtf(var + 1e-5f);
    const int b = bh >> 3, h = bh & 7;
    out[(size_t)b * 512 + h * 64 + tid] = o * gnw[h] + gnb[h];
  }
}

extern "C" void kernel_launch(void* const* d_in, const int* in_sizes, int n_in,
                              void* d_out, int out_size, void* d_ws,
                              size_t ws_size, hipStream_t stream) {
  (void)in_sizes; (void)n_in; (void)out_size; (void)ws_size;
  const float* emb  = (const float*)d_in[0];
  const float* W    = (const float*)d_in[1];
  const float* bias = (const float*)d_in[2];
  const float* gnw  = (const float*)d_in[3];
  const float* gnb  = (const float*)d_in[4];
  float* out = (float*)d_out;

  char* ws = (char*)d_ws;
  const size_t perQ = (size_t)BH * L_SEQ * DQ;        // 4,194,304 elems
  unsigned short* embB = (unsigned short*)ws;                      // 8 MB
  unsigned short* WB   = (unsigned short*)(ws + 8u * 1024 * 1024); // 1.5 MB
  unsigned short* Qb   = (unsigned short*)(ws + 10u * 1024 * 1024);
  unsigned short* Kb   = Qb + perQ;   // @18M
  unsigned short* Vb   = Kb + perQ;   // @26M
  float* Oacc = (float*)(ws + 35u * 1024 * 1024);     // 16 KB
  int*   cnt  = (int*)(ws + 35u * 1024 * 1024 + 64u * 1024);

  to_bf16<<<dim3(2432), 256, 0, stream>>>(emb, W, embB, WB, Oacc, cnt);
  qkv_mfma<<<dim3(768), 256, 0, stream>>>(embB, WB, bias, Qb, Kb, Vb);
  attn_one<<<dim3(512), 256, 0, stream>>>(Qb, Kb, Vb, gnw, gnb,
                                          Oacc, cnt, out);
}